// Round 3
// baseline (262.735 us; speedup 1.0000x reference)
//
#include <hip/hip_runtime.h>
#include <math.h>

#define NGRID 343
#define NPATH 20

// ---------------- compile-time Clifford tables (Cl(3,0), blade order:
// 1, e1, e2, e3, e12, e13, e23, e123) ----------------
struct Tab {
  int prod_idx[8][8];
  int prod_sgn[8][8];
  int pid[4][4][4];
  int grade[8];
  int kk_idx[8][8];
  int kk_sgn[8][8];
};

constexpr Tab make_tab() {
  Tab t{};
  int mask[8]  = {0,1,2,4,3,5,6,7};
  int idxof[8] = {0,1,2,4,3,5,6,7};
  for (int k = 0; k < 8; ++k) {
    int g = 0;
    for (int b = 0; b < 3; ++b) g += (mask[k] >> b) & 1;
    t.grade[k] = g;
  }
  for (int k = 0; k < 8; ++k)
    for (int m = 0; m < 8; ++m) {
      int A = mask[k], B = mask[m];
      t.prod_idx[k][m] = idxof[A ^ B];
      int c = 0;
      for (int i = 0; i < 3; ++i)
        if ((B >> i) & 1)
          for (int j = i + 1; j < 3; ++j)
            if ((A >> j) & 1) c++;
      t.prod_sgn[k][m] = (c & 1) ? -1 : 1;
    }
  int pc = 0;
  for (int a = 0; a < 4; ++a)
    for (int b = 0; b < 4; ++b)
      for (int c = 0; c < 4; ++c) {
        bool ok = false;
        for (int k = 0; k < 8; ++k)
          for (int m = 0; m < 8; ++m)
            if (t.grade[k] == a && t.grade[m] == c &&
                t.grade[t.prod_idx[k][m]] == b)
              ok = true;
        t.pid[a][b][c] = ok ? pc++ : NPATH;
      }
  for (int l = 0; l < 8; ++l)
    for (int m = 0; m < 8; ++m)
      for (int k = 0; k < 8; ++k)
        if (t.prod_idx[k][m] == l) {
          t.kk_idx[l][m] = k;
          t.kk_sgn[l][m] = t.prod_sgn[k][m];
        }
  return t;
}
constexpr Tab TB = make_tab();

__device__ __forceinline__ int gradeOf(int b) {
  return (b == 0) ? 0 : (b < 4) ? 1 : (b < 7) ? 2 : 3;
}

// ---------------- workspace layout (floats) ----------------
// lin0_t [4][33][64]     @ 0        (8448)    ([g][ch][hh])
// gps_t  [4][64][64][20] @ 8448     (327680)  ([l][i][o][p]) -> float4-able
// outW_t [1024][64][4]   @ 336128   (262144)  ([oc][i][g])   -> float4-able
// k_ws   [343][1024][8]  @ 598272   (2809856) ([n][oc][b])
#define OFF_LIN0T 0
#define OFF_GPST  8448
#define OFF_OUTWT 336128
#define OFF_KWS   598272

// ---------------- kernel 0: weight transpose ----------------
__global__ void ccs_prep_kernel(const float* __restrict__ lin0_W,
                                const float* __restrict__ gps_w,
                                const float* __restrict__ out_W,
                                float* __restrict__ ws) {
  const int TOT = 8448 + 327680 + 262144;
  for (int d = blockIdx.x * blockDim.x + threadIdx.x; d < TOT;
       d += gridDim.x * blockDim.x) {
    float v;
    if (d < 8448) {
      int hh = d & 63, ch = (d >> 6) % 33, g = (d >> 6) / 33;
      v = lin0_W[(g * 64 + hh) * 33 + ch];
    } else if (d < OFF_OUTWT) {
      int idx = d - OFF_GPST;
      int p = idx % 20, r = idx / 20;
      int o = r & 63, i = (r >> 6) & 63, l = r >> 12;
      v = gps_w[(((size_t)l * 64 + o) * 64 + i) * 20 + p];
    } else {
      int idx = d - OFF_OUTWT;
      int g = idx & 3, i = (idx >> 2) & 63, oc = idx >> 8;
      v = out_W[(g * 1024 + oc) * 64 + i];
    }
    ws[d] = v;
  }
}

// ---------------- kernel 1: per-grid-point network ----------------
__global__ __launch_bounds__(1024, 4)
void ccs_net_kernel(const float* __restrict__ condition,
                    const float* __restrict__ rel_pos_sigma,
                    const float* __restrict__ lin0_b,
                    const float* __restrict__ act0_a,
                    const float* __restrict__ act0_b,
                    const float* __restrict__ lins_W,
                    const float* __restrict__ lins_b,
                    const float* __restrict__ acts_a,
                    const float* __restrict__ acts_b,
                    const float* __restrict__ out_b,
                    const float* __restrict__ shell_sigma,
                    const float* __restrict__ ws,
                    float* __restrict__ kws) {
  const float* lin0t = ws + OFF_LIN0T;
  const float* gpst  = ws + OFF_GPST;
  const float* outwt = ws + OFF_OUTWT;

  __shared__ __align__(16) float xb[264];      // [ch][b]
  __shared__ __align__(16) float F0[512];      // blade-major [b][64] (final: i-major)
  __shared__ __align__(16) float F1[512];
  __shared__ __align__(16) float part[8192];   // [j][isub][o]

  const int n = blockIdx.x;
  const int tid = threadIdx.x;
  const int iz = n % 7, iy = (n / 7) % 7, ix = n / 49;
  const float px = (float)ix - 3.f, py = (float)iy - 3.f, pz = (float)iz - 3.f;
  const float q = px * px + py * py + pz * pz;
  const float sig = rel_pos_sigma[0];
  const float scal = expf(-q / (2.f * sig * sig));

  if (tid < 264) {
    int ch = tid >> 3, b = tid & 7;
    float v;
    if (ch == 0)
      v = (b == 0) ? scal : (b == 1) ? px : (b == 2) ? py : (b == 3) ? pz : 0.f;
    else
      v = condition[(ch - 1) * 8 + b];
    xb[tid] = v;
  }
  __syncthreads();

  const int hh = tid & 63;
  const int bb = (tid >> 6) & 7;
  const bool act512 = tid < 512;

  // ---- lin0: xb -> F0 (blade-major) ----
  if (act512) {
    int g = gradeOf(bb);
    float acc = (bb == 0) ? lin0_b[hh] : 0.f;
    const float* wrow = lin0t + g * (33 * 64) + hh;
    #pragma unroll
    for (int ch = 0; ch < 33; ++ch)
      acc = fmaf(wrow[ch * 64], xb[ch * 8 + bb], acc);
    F0[bb * 64 + hh] = acc;
  }
  __syncthreads();

  auto silu = [&](const float* src, float* dst, const float* aa,
                  const float* ab) {
    if (act512) {
      int g = gradeOf(bb);
      int s0 = (g == 0) ? 0 : (g == 1) ? 1 : (g == 2) ? 4 : 7;
      int cnt = (g == 0 || g == 3) ? 1 : 3;
      float qg = 0.f;
      for (int u = 0; u < cnt; ++u) {
        float v = src[(s0 + u) * 64 + hh];
        qg = fmaf(v, v, qg);
      }
      float z = fmaf(aa[hh * 4 + g], qg, ab[hh * 4 + g]);
      float gate = 1.f / (1.f + expf(-z));
      dst[bb * 64 + hh] = src[bb * 64 + hh] * gate;
    }
  };

  auto lin = [&](const float* src, float* dst, const float* wl,
                 const float* bias) {
    if (act512) {
      int g = gradeOf(bb);
      float acc = (bb == 0) ? bias[hh] : 0.f;
      const float4* wr = (const float4*)(wl + ((size_t)g * 64 + hh) * 64);
      #pragma unroll
      for (int u = 0; u < 16; ++u) {
        float4 w = wr[u];
        const float* s = src + bb * 64 + u * 4;
        acc = fmaf(w.x, s[0], acc);
        acc = fmaf(w.y, s[1], acc);
        acc = fmaf(w.z, s[2], acc);
        acc = fmaf(w.w, s[3], acc);
      }
      dst[bb * 64 + hh] = acc;
    }
  };

  auto gp = [&](const float* src, float* dst, const float* wl, bool imaj) {
    const int o = tid & 63;
    const int isub = tid >> 6;  // 0..15
    float facc[8];
    #pragma unroll
    for (int j = 0; j < 8; ++j) facc[j] = 0.f;
    #pragma unroll
    for (int it = 0; it < 4; ++it) {
      const int i = isub * 4 + it;
      float x8[8];
      #pragma unroll
      for (int b = 0; b < 8; ++b) x8[b] = src[b * 64 + i];  // broadcast
      float4 w4[5];
      const float4* wb = (const float4*)(wl + ((size_t)i * 64 + o) * 20);
      #pragma unroll
      for (int u = 0; u < 5; ++u) w4[u] = wb[u];
      const float* wp = (const float*)w4;
      // diagonal k==m (output blade 0)
      #pragma unroll
      for (int k = 0; k < 8; ++k) {
        const int p = TB.pid[TB.grade[k]][0][TB.grade[k]];
        float tp = x8[k] * x8[k];
        facc[0] = fmaf(TB.prod_sgn[k][k] > 0 ? tp : -tp, wp[p], facc[0]);
      }
      // off-diagonal pairs (k<m): share the x-product
      #pragma unroll
      for (int k = 0; k < 8; ++k) {
        #pragma unroll
        for (int m = k + 1; m < 8; ++m) {
          const int j  = TB.prod_idx[k][m];
          const int p1 = TB.pid[TB.grade[k]][TB.grade[j]][TB.grade[m]];
          const int p2 = TB.pid[TB.grade[m]][TB.grade[j]][TB.grade[k]];
          const float w1 = (TB.prod_sgn[k][m] > 0) ? wp[p1] : -wp[p1];
          const float w2 = (TB.prod_sgn[m][k] > 0) ? wp[p2] : -wp[p2];
          facc[j] = fmaf(x8[k] * x8[m], w1 + w2, facc[j]);
        }
      }
    }
    #pragma unroll
    for (int j = 0; j < 8; ++j) part[(j * 16 + isub) * 64 + o] = facc[j];
    __syncthreads();
    if (act512) {
      const int o2 = tid & 63, j2 = tid >> 6;
      float s = 0.f;
      #pragma unroll
      for (int u = 0; u < 16; ++u) s += part[(j2 * 16 + u) * 64 + o2];
      s *= 0.125f;
      if (imaj)
        dst[o2 * 8 + j2] = s;
      else
        dst[j2 * 64 + o2] = s;
    }
    __syncthreads();
  };

  // ---- layer 0 ----
  silu(F0, F1, act0_a, act0_b);
  __syncthreads();
  gp(F1, F0, gpst + 0, false);  // features (blade-major) in F0

  // ---- layers 1..3 ----
  float* f = F0;
  float* g_ = F1;
  #pragma unroll 1
  for (int l = 0; l < 3; ++l) {
    lin(f, g_, lins_W + (size_t)l * 16384, lins_b + l * 64);
    __syncthreads();
    silu(g_, f, acts_a + l * 256, acts_b + l * 256);
    __syncthreads();
    gp(f, g_, gpst + (size_t)(l + 1) * 81920, l == 2);
    float* t = f; f = g_; g_ = t;  // features in f (last: i-major)
  }

  // ---- output linear + shell (f is i-major [i][b]) ----
  const float FACTOR = 1.0f / sqrtf(343.0f);
  const int oc = tid;
  float acc[8];
  #pragma unroll
  for (int b = 0; b < 8; ++b) acc[b] = 0.f;
  acc[0] = out_b[oc];
  const float4* wv = (const float4*)(outwt + (size_t)oc * 256);
  #pragma unroll 8
  for (int i = 0; i < 64; ++i) {
    float4 w = wv[i];
    const float4* hp = (const float4*)(f + i * 8);
    float4 h0 = hp[0], h1 = hp[1];
    acc[0] = fmaf(w.x, h0.x, acc[0]);
    acc[1] = fmaf(w.y, h0.y, acc[1]);
    acc[2] = fmaf(w.y, h0.z, acc[2]);
    acc[3] = fmaf(w.y, h0.w, acc[3]);
    acc[4] = fmaf(w.z, h1.x, acc[4]);
    acc[5] = fmaf(w.z, h1.y, acc[5]);
    acc[6] = fmaf(w.z, h1.z, acc[6]);
    acc[7] = fmaf(w.w, h1.w, acc[7]);
  }
  float4 s0 = ((const float4*)(shell_sigma + oc * 8))[0];
  float4 s1 = ((const float4*)(shell_sigma + oc * 8))[1];
  float o8[8];
  o8[0] = acc[0] * expf(-q / (s0.x * s0.x)) * FACTOR;
  o8[1] = acc[1] * expf(-q / (s0.y * s0.y)) * FACTOR;
  o8[2] = acc[2] * expf(-q / (s0.z * s0.z)) * FACTOR;
  o8[3] = acc[3] * expf(-q / (s0.w * s0.w)) * FACTOR;
  o8[4] = acc[4] * expf(-q / (s1.x * s1.x)) * FACTOR;
  o8[5] = acc[5] * expf(-q / (s1.y * s1.y)) * FACTOR;
  o8[6] = acc[6] * expf(-q / (s1.z * s1.z)) * FACTOR;
  o8[7] = acc[7] * expf(-q / (s1.w * s1.w)) * FACTOR;
  float4* dst = (float4*)(kws + ((size_t)n * 1024 + oc) * 8);
  dst[0] = make_float4(o8[0], o8[1], o8[2], o8[3]);
  dst[1] = make_float4(o8[4], o8[5], o8[6], o8[7]);
}

// ---------------- kernel 2: Cayley expansion to output ----------------
__global__ __launch_bounds__(256)
void ccs_expand_kernel(const float* __restrict__ cayley_w,
                       const float* __restrict__ kws,
                       float* __restrict__ out) {
  const int oi = blockIdx.x;  // o*32 + i
  const int o = oi >> 5, i = oi & 31;
  const int tid = threadIdx.x;
  __shared__ float sk[343 * 9];  // padded stride 9 -> conflict-free reads

  for (int idx = tid; idx < 686; idx += 256) {
    int nn = idx >> 1, h = (idx & 1) * 4;
    float4 v = *(const float4*)(kws + ((size_t)nn * 1024 + oi) * 8 + h);
    float* s = sk + nn * 9 + h;
    s[0] = v.x; s[1] = v.y; s[2] = v.z; s[3] = v.w;
  }
  float cw[20];
  #pragma unroll
  for (int p = 0; p < 20; ++p) cw[p] = cayley_w[oi * 20 + p];
  __syncthreads();

  #pragma unroll
  for (int l = 0; l < 8; ++l) {
    #pragma unroll
    for (int m = 0; m < 8; ++m) {
      const int kk = TB.kk_idx[l][m];
      const int p = TB.pid[TB.grade[kk]][TB.grade[l]][TB.grade[m]];
      const float wv = (TB.kk_sgn[l][m] > 0) ? cw[p] : -cw[p];
      float* orow = out + ((size_t)((o * 8 + l) * 256 + i * 8 + m)) * 343;
      for (int c = tid; c < 343; c += 256) orow[c] = sk[c * 9 + kk] * wv;
    }
  }
}

extern "C" void kernel_launch(void* const* d_in, const int* in_sizes, int n_in,
                              void* d_out, int out_size, void* d_ws,
                              size_t ws_size, hipStream_t stream) {
  const float* condition     = (const float*)d_in[0];
  const float* rel_pos_sigma = (const float*)d_in[1];
  const float* cayley_w      = (const float*)d_in[2];
  const float* lin0_W        = (const float*)d_in[3];
  const float* lin0_b        = (const float*)d_in[4];
  const float* act0_a        = (const float*)d_in[5];
  const float* act0_b        = (const float*)d_in[6];
  const float* gps_w         = (const float*)d_in[7];
  const float* lins_W        = (const float*)d_in[8];
  const float* lins_b        = (const float*)d_in[9];
  const float* acts_a        = (const float*)d_in[10];
  const float* acts_b        = (const float*)d_in[11];
  const float* out_W         = (const float*)d_in[12];
  const float* out_b         = (const float*)d_in[13];
  const float* shell_sigma   = (const float*)d_in[14];

  float* ws = (float*)d_ws;
  float* kws = ws + OFF_KWS;
  float* out = (float*)d_out;

  ccs_prep_kernel<<<dim3(640), dim3(256), 0, stream>>>(lin0_W, gps_w, out_W,
                                                       ws);
  ccs_net_kernel<<<dim3(343), dim3(1024), 0, stream>>>(
      condition, rel_pos_sigma, lin0_b, act0_a, act0_b, lins_W, lins_b, acts_a,
      acts_b, out_b, shell_sigma, ws, kws);
  ccs_expand_kernel<<<dim3(1024), dim3(256), 0, stream>>>(cayley_w, kws, out);
}